// Round 1
// baseline (540.202 us; speedup 1.0000x reference)
//
#include <hip/hip_runtime.h>

#define ROWS 8192
#define NCOL 2048
#define THREADS 256

// One block per row: load pred-row and targ-row into LDS, bitonic-sort both
// (sharing the same barriers), then reduce sum((p_sorted - t_sorted)^2) into
// a per-row partial in d_ws. Second kernel reduces the 8192 partials.
__global__ __launch_bounds__(THREADS) void sort_mse_kernel(
    const float* __restrict__ pred, const float* __restrict__ targ,
    float* __restrict__ partial) {
  __shared__ float sp[NCOL];
  __shared__ float st[NCOL];
  const int row = blockIdx.x;
  const size_t base = (size_t)row * NCOL;

  for (int i = threadIdx.x; i < NCOL; i += THREADS) {
    sp[i] = pred[base + i];
    st[i] = targ[base + i];
  }
  __syncthreads();

  // Bitonic sort, ascending. 66 passes; both arrays per pass.
  for (int k = 2; k <= NCOL; k <<= 1) {
    for (int j = k >> 1; j > 0; j >>= 1) {
#pragma unroll
      for (int q = 0; q < (NCOL / 2) / THREADS; ++q) {
        const int pr = threadIdx.x + q * THREADS;           // pair id [0, N/2)
        const int i = ((pr & ~(j - 1)) << 1) | (pr & (j - 1));
        const int ixj = i | j;                               // partner (i's j-bit is 0)
        const bool up = ((i & k) == 0);
        float a = sp[i], b = sp[ixj];
        if ((a > b) == up) { sp[i] = b; sp[ixj] = a; }
        float c = st[i], d = st[ixj];
        if ((c > d) == up) { st[i] = d; st[ixj] = c; }
      }
      __syncthreads();
    }
  }

  // Per-block reduction of squared differences.
  float acc = 0.f;
  for (int i = threadIdx.x; i < NCOL; i += THREADS) {
    const float d = sp[i] - st[i];
    acc += d * d;
  }
#pragma unroll
  for (int off = 32; off > 0; off >>= 1) acc += __shfl_down(acc, off);

  __shared__ float wsum[THREADS / 64];
  if ((threadIdx.x & 63) == 0) wsum[threadIdx.x >> 6] = acc;
  __syncthreads();
  if (threadIdx.x == 0) {
    float s = 0.f;
#pragma unroll
    for (int w = 0; w < THREADS / 64; ++w) s += wsum[w];
    partial[row] = s;
  }
}

__global__ __launch_bounds__(256) void reduce_kernel(
    const float* __restrict__ partial, float* __restrict__ out) {
  float acc = 0.f;
  for (int i = threadIdx.x; i < ROWS; i += 256) acc += partial[i];
#pragma unroll
  for (int off = 32; off > 0; off >>= 1) acc += __shfl_down(acc, off);
  __shared__ float wsum[4];
  if ((threadIdx.x & 63) == 0) wsum[threadIdx.x >> 6] = acc;
  __syncthreads();
  if (threadIdx.x == 0) {
    const float s = wsum[0] + wsum[1] + wsum[2] + wsum[3];
    out[0] = s * (1.0f / ((float)ROWS * (float)NCOL));
  }
}

extern "C" void kernel_launch(void* const* d_in, const int* in_sizes, int n_in,
                              void* d_out, int out_size, void* d_ws, size_t ws_size,
                              hipStream_t stream) {
  const float* pred = (const float*)d_in[0];
  const float* targ = (const float*)d_in[1];
  float* out = (float*)d_out;
  float* partial = (float*)d_ws;  // 8192 floats = 32 KiB, all written before read

  sort_mse_kernel<<<ROWS, THREADS, 0, stream>>>(pred, targ, partial);
  reduce_kernel<<<1, 256, 0, stream>>>(partial, out);
}

// Round 2
// 474.387 us; speedup vs baseline: 1.1387x; 1.1387x over previous
//
#include <hip/hip_runtime.h>

#define ROWS 8192
#define NCOL 2048
#define WT 64   // one wave per block
#define V 32    // elements per thread: 64 * 32 = 2048

// One wave per row. Each lane holds V=32 consecutive elements (e = lane*32+v)
// of both pred and targ in registers. Full bitonic sort of both arrays:
//   j <  32 : register compare-exchange within the lane (no LDS at all)
//   j >= 32 : partner lane = lane ^ (j/32) <= 32  -> __shfl_xor within wave64
// No shared memory, no barriers. Then sum (p_(r)-t_(r))^2 and write one
// partial per row; second kernel reduces the 8192 partials.
__global__ __launch_bounds__(WT) void sort_mse_kernel(
    const float* __restrict__ pred, const float* __restrict__ targ,
    float* __restrict__ partial) {
  const int lane = threadIdx.x;
  const int row = blockIdx.x;
  const size_t base = (size_t)row * NCOL + (size_t)lane * V;

  float rp[V], rt[V];
  const float4* p4 = (const float4*)(pred + base);
  const float4* t4 = (const float4*)(targ + base);
#pragma unroll
  for (int q = 0; q < V / 4; ++q) {
    float4 a = p4[q];
    rp[4 * q + 0] = a.x; rp[4 * q + 1] = a.y;
    rp[4 * q + 2] = a.z; rp[4 * q + 3] = a.w;
    float4 b = t4[q];
    rt[4 * q + 0] = b.x; rt[4 * q + 1] = b.y;
    rt[4 * q + 2] = b.z; rt[4 * q + 3] = b.w;
  }

#pragma unroll
  for (int k = 2; k <= NCOL; k <<= 1) {
#pragma unroll
    for (int j = k >> 1; j > 0; j >>= 1) {
      if (j >= V) {
        // cross-lane stage: partner lane = lane ^ m, m in {1,2,4,8,16,32}
        const int m = j / V;
        const bool up = ((lane & (k / V)) == 0);   // k >= 64 here
        const bool low = ((lane & m) == 0);
        const bool take_min = (low == up);
#pragma unroll
        for (int v = 0; v < V; ++v) {
          const float op = __shfl_xor(rp[v], m, 64);
          const float ot = __shfl_xor(rt[v], m, 64);
          rp[v] = take_min ? fminf(rp[v], op) : fmaxf(rp[v], op);
          rt[v] = take_min ? fminf(rt[v], ot) : fmaxf(rt[v], ot);
        }
      } else {
        // in-lane stage: pair (v, v|j) in registers
#pragma unroll
        for (int v = 0; v < V; ++v) {
          if ((v & j) == 0) {
            const int w = v | j;
            // up = ((e & k) == 0), e = lane*32 + v
            const bool up = (k <= 16) ? ((v & k) == 0)
                                      : ((lane & (k / V)) == 0);
            const float a = rp[v], b = rp[w];
            const float lo = fminf(a, b), hi = fmaxf(a, b);
            rp[v] = up ? lo : hi;
            rp[w] = up ? hi : lo;
            const float c = rt[v], d = rt[w];
            const float lo2 = fminf(c, d), hi2 = fmaxf(c, d);
            rt[v] = up ? lo2 : hi2;
            rt[w] = up ? hi2 : lo2;
          }
        }
      }
    }
  }

  // ranks are matched at identical (lane, v) after both sorts
  float acc = 0.f;
#pragma unroll
  for (int v = 0; v < V; ++v) {
    const float d = rp[v] - rt[v];
    acc = fmaf(d, d, acc);
  }
#pragma unroll
  for (int off = 32; off > 0; off >>= 1) acc += __shfl_down(acc, off, 64);
  if (lane == 0) partial[row] = acc;
}

__global__ __launch_bounds__(256) void reduce_kernel(
    const float* __restrict__ partial, float* __restrict__ out) {
  float acc = 0.f;
  for (int i = threadIdx.x; i < ROWS; i += 256) acc += partial[i];
#pragma unroll
  for (int off = 32; off > 0; off >>= 1) acc += __shfl_down(acc, off, 64);
  __shared__ float wsum[4];
  if ((threadIdx.x & 63) == 0) wsum[threadIdx.x >> 6] = acc;
  __syncthreads();
  if (threadIdx.x == 0) {
    const float s = wsum[0] + wsum[1] + wsum[2] + wsum[3];
    out[0] = s * (1.0f / ((float)ROWS * (float)NCOL));
  }
}

extern "C" void kernel_launch(void* const* d_in, const int* in_sizes, int n_in,
                              void* d_out, int out_size, void* d_ws, size_t ws_size,
                              hipStream_t stream) {
  const float* pred = (const float*)d_in[0];
  const float* targ = (const float*)d_in[1];
  float* out = (float*)d_out;
  float* partial = (float*)d_ws;  // 8192 floats, every slot written each call

  sort_mse_kernel<<<ROWS, WT, 0, stream>>>(pred, targ, partial);
  reduce_kernel<<<1, 256, 0, stream>>>(partial, out);
}

// Round 3
// 285.028 us; speedup vs baseline: 1.8953x; 1.6644x over previous
//
#include <hip/hip_runtime.h>

#define ROWS 8192
#define NCOL 2048
#define V 32
#define WPB 4                 // waves (rows) per block
#define THREADS (WPB * 64)

// static compare-exchange: ascending, both indices compile-time
__device__ __forceinline__ void ce(float& a, float& b) {
  const float lo = fminf(a, b);
  const float hi = fmaxf(a, b);
  a = lo; b = hi;
}

// One wave per row; lane holds elements e = lane*32 + v (v = 0..31) of both
// arrays in registers. Normalized bitonic sort (all compares ascending):
//   stage k: flip pass (partner = e ^ (k-1)), then xor passes j = k/4 .. 1.
// k <= 32: fully in-lane, all indices AND directions compile-time (2 VALU/CE).
// k >= 64: flip = cross-lane (lane^(2kb-1), v^31), xor j>=32 cross-lane
// (lane^m), j<=16 in-lane static. Cross-lane direction is one lane bit ->
// exec-branch: lower lanes do all-min, upper all-max (3 issues/elem).
__global__ __launch_bounds__(THREADS) void sort_mse_kernel(
    const float* __restrict__ pred, const float* __restrict__ targ,
    float* __restrict__ partial) {
  const int lane = threadIdx.x & 63;
  const int wave = threadIdx.x >> 6;
  const int row = blockIdx.x * WPB + wave;
  const size_t base = (size_t)row * NCOL + (size_t)lane * V;

  float rp[V], rt[V];
  const float4* p4 = (const float4*)(pred + base);
  const float4* t4 = (const float4*)(targ + base);
#pragma unroll
  for (int q = 0; q < V / 4; ++q) {
    const float4 a = p4[q];
    rp[4 * q + 0] = a.x; rp[4 * q + 1] = a.y;
    rp[4 * q + 2] = a.z; rp[4 * q + 3] = a.w;
    const float4 b = t4[q];
    rt[4 * q + 0] = b.x; rt[4 * q + 1] = b.y;
    rt[4 * q + 2] = b.z; rt[4 * q + 3] = b.w;
  }

  // ---- Phase 1: stages k = 2..32, fully in-lane, fully static ----
#pragma unroll
  for (int k = 2; k <= V; k <<= 1) {
    // flip pass: pairs (v, v^(k-1)), enumerate v with bit k/2 clear
#pragma unroll
    for (int v = 0; v < V; ++v) {
      if ((v & (k >> 1)) == 0) {
        ce(rp[v], rp[v ^ (k - 1)]);
        ce(rt[v], rt[v ^ (k - 1)]);
      }
    }
#pragma unroll
    for (int j = k >> 2; j >= 1; j >>= 1) {
#pragma unroll
      for (int v = 0; v < V; ++v) {
        if ((v & j) == 0) {
          ce(rp[v], rp[v | j]);
          ce(rt[v], rt[v | j]);
        }
      }
    }
  }

  // ---- Phase 2: stages k = 64..2048 (kb = k/64 = 1..32) ----
  // kb-loop intentionally NOT unrolled (I-cache); register indices inside
  // are all compile-time.
  for (int kb = 1; kb <= 32; kb <<= 1) {
    // flip pass: partner lane = lane ^ (2kb-1), partner elem = v ^ 31,
    // keep min iff (lane & kb) == 0.
    {
      const int lm = 2 * kb - 1;
      const bool lower = (lane & kb) == 0;
#pragma unroll
      for (int q = 0; q < 4; ++q) {
        // self-contained unit: vA = 4q..4q+3 and vB = vA^31 (reads only
        // within the unit, so no read-after-update hazard across units)
        float op[8], ot[8];
#pragma unroll
        for (int u = 0; u < 4; ++u) {
          const int vA = 4 * q + u;
          const int vB = vA ^ 31;
          op[u]     = __shfl_xor(rp[vB], lm, 64);  // partner value for pos vA
          ot[u]     = __shfl_xor(rt[vB], lm, 64);
          op[u + 4] = __shfl_xor(rp[vA], lm, 64);  // partner value for pos vB
          ot[u + 4] = __shfl_xor(rt[vA], lm, 64);
        }
        if (lower) {
#pragma unroll
          for (int u = 0; u < 4; ++u) {
            const int vA = 4 * q + u, vB = vA ^ 31;
            rp[vA] = fminf(rp[vA], op[u]);     rt[vA] = fminf(rt[vA], ot[u]);
            rp[vB] = fminf(rp[vB], op[u + 4]); rt[vB] = fminf(rt[vB], ot[u + 4]);
          }
        } else {
#pragma unroll
          for (int u = 0; u < 4; ++u) {
            const int vA = 4 * q + u, vB = vA ^ 31;
            rp[vA] = fmaxf(rp[vA], op[u]);     rt[vA] = fmaxf(rt[vA], ot[u]);
            rp[vB] = fmaxf(rp[vB], op[u + 4]); rt[vB] = fmaxf(rt[vB], ot[u + 4]);
          }
        }
      }
    }
    // cross-lane xor passes: lane mask m = kb/2 .. 1, same v, keep min iff
    // (lane & m) == 0. Lockstep same-v exchange is hazard-free.
    for (int m = kb >> 1; m >= 1; m >>= 1) {
      const bool lower = (lane & m) == 0;
#pragma unroll
      for (int c = 0; c < V; c += 8) {
        float op[8], ot[8];
#pragma unroll
        for (int u = 0; u < 8; ++u) {
          op[u] = __shfl_xor(rp[c + u], m, 64);
          ot[u] = __shfl_xor(rt[c + u], m, 64);
        }
        if (lower) {
#pragma unroll
          for (int u = 0; u < 8; ++u) {
            rp[c + u] = fminf(rp[c + u], op[u]);
            rt[c + u] = fminf(rt[c + u], ot[u]);
          }
        } else {
#pragma unroll
          for (int u = 0; u < 8; ++u) {
            rp[c + u] = fmaxf(rp[c + u], op[u]);
            rt[c + u] = fmaxf(rt[c + u], ot[u]);
          }
        }
      }
    }
    // in-lane xor passes j = 16..1: static indices AND static direction
#pragma unroll
    for (int j = 16; j >= 1; j >>= 1) {
#pragma unroll
      for (int v = 0; v < V; ++v) {
        if ((v & j) == 0) {
          ce(rp[v], rp[v | j]);
          ce(rt[v], rt[v | j]);
        }
      }
    }
  }

  // ranks are matched at identical (lane, v) after both sorts
  float acc = 0.f;
#pragma unroll
  for (int v = 0; v < V; ++v) {
    const float d = rp[v] - rt[v];
    acc = fmaf(d, d, acc);
  }
#pragma unroll
  for (int off = 32; off > 0; off >>= 1) acc += __shfl_down(acc, off, 64);
  if (lane == 0) partial[row] = acc;
}

__global__ __launch_bounds__(256) void reduce_kernel(
    const float* __restrict__ partial, float* __restrict__ out) {
  float acc = 0.f;
  for (int i = threadIdx.x; i < ROWS; i += 256) acc += partial[i];
#pragma unroll
  for (int off = 32; off > 0; off >>= 1) acc += __shfl_down(acc, off, 64);
  __shared__ float wsum[4];
  if ((threadIdx.x & 63) == 0) wsum[threadIdx.x >> 6] = acc;
  __syncthreads();
  if (threadIdx.x == 0) {
    const float s = wsum[0] + wsum[1] + wsum[2] + wsum[3];
    out[0] = s * (1.0f / ((float)ROWS * (float)NCOL));
  }
}

extern "C" void kernel_launch(void* const* d_in, const int* in_sizes, int n_in,
                              void* d_out, int out_size, void* d_ws, size_t ws_size,
                              hipStream_t stream) {
  const float* pred = (const float*)d_in[0];
  const float* targ = (const float*)d_in[1];
  float* out = (float*)d_out;
  float* partial = (float*)d_ws;  // 8192 floats, every slot written each call

  sort_mse_kernel<<<ROWS / WPB, THREADS, 0, stream>>>(pred, targ, partial);
  reduce_kernel<<<1, 256, 0, stream>>>(partial, out);
}

// Round 4
// 269.351 us; speedup vs baseline: 2.0056x; 1.0582x over previous
//
#include <hip/hip_runtime.h>

#define ROWS 8192
#define NCOL 2048
#define V 32
#define WPB 4                 // waves (rows) per block
#define THREADS (WPB * 64)

// static compare-exchange: ascending, both indices compile-time
__device__ __forceinline__ void ce(float& a, float& b) {
  const float lo = fminf(a, b);
  const float hi = fmaxf(a, b);
  a = lo; b = hi;
}

// One wave per row; lane holds elements e = lane*32 + v of both arrays in
// registers. Normalized bitonic sort (all compares ascending).
// __launch_bounds__(256,4): cap VGPR at 128 -> 4 waves/SIMD (was ~3).
// Single kernel: each wave atomically adds its scaled row-sum into out[0]
// (out zeroed by hipMemsetAsync in kernel_launch).
__global__ __launch_bounds__(THREADS, 4) void sort_mse_kernel(
    const float* __restrict__ pred, const float* __restrict__ targ,
    float* __restrict__ out) {
  const int lane = threadIdx.x & 63;
  const int wave = threadIdx.x >> 6;
  const int row = blockIdx.x * WPB + wave;
  const size_t base = (size_t)row * NCOL + (size_t)lane * V;

  float rp[V], rt[V];
  const float4* p4 = (const float4*)(pred + base);
  const float4* t4 = (const float4*)(targ + base);
#pragma unroll
  for (int q = 0; q < V / 4; ++q) {
    const float4 a = p4[q];
    rp[4 * q + 0] = a.x; rp[4 * q + 1] = a.y;
    rp[4 * q + 2] = a.z; rp[4 * q + 3] = a.w;
    const float4 b = t4[q];
    rt[4 * q + 0] = b.x; rt[4 * q + 1] = b.y;
    rt[4 * q + 2] = b.z; rt[4 * q + 3] = b.w;
  }

  // ---- Phase 1: stages k = 2..32, fully in-lane, fully static ----
#pragma unroll
  for (int k = 2; k <= V; k <<= 1) {
#pragma unroll
    for (int v = 0; v < V; ++v) {
      if ((v & (k >> 1)) == 0) {
        ce(rp[v], rp[v ^ (k - 1)]);
        ce(rt[v], rt[v ^ (k - 1)]);
      }
    }
#pragma unroll
    for (int j = k >> 2; j >= 1; j >>= 1) {
#pragma unroll
      for (int v = 0; v < V; ++v) {
        if ((v & j) == 0) {
          ce(rp[v], rp[v | j]);
          ce(rt[v], rt[v | j]);
        }
      }
    }
  }

  // ---- Phase 2: stages k = 64..2048 (kb = k/64 = 1..32) ----
  for (int kb = 1; kb <= 32; kb <<= 1) {
    // flip pass: partner lane = lane ^ (2kb-1), partner elem = v ^ 31,
    // keep min iff (lane & kb) == 0. One 8-float temp buffer; p then t.
    {
      const int lm = 2 * kb - 1;
      const bool lower = (lane & kb) == 0;
#pragma unroll
      for (int q = 0; q < 4; ++q) {
        const int vA = 4 * q;          // unit: vA..vA+3 and their ^31 partners
        float o[8];
#pragma unroll
        for (int u = 0; u < 4; ++u) {
          o[u]     = __shfl_xor(rp[(vA + u) ^ 31], lm, 64);
          o[u + 4] = __shfl_xor(rp[vA + u], lm, 64);
        }
        if (lower) {
#pragma unroll
          for (int u = 0; u < 4; ++u) {
            rp[vA + u]        = fminf(rp[vA + u], o[u]);
            rp[(vA + u) ^ 31] = fminf(rp[(vA + u) ^ 31], o[u + 4]);
          }
        } else {
#pragma unroll
          for (int u = 0; u < 4; ++u) {
            rp[vA + u]        = fmaxf(rp[vA + u], o[u]);
            rp[(vA + u) ^ 31] = fmaxf(rp[(vA + u) ^ 31], o[u + 4]);
          }
        }
#pragma unroll
        for (int u = 0; u < 4; ++u) {
          o[u]     = __shfl_xor(rt[(vA + u) ^ 31], lm, 64);
          o[u + 4] = __shfl_xor(rt[vA + u], lm, 64);
        }
        if (lower) {
#pragma unroll
          for (int u = 0; u < 4; ++u) {
            rt[vA + u]        = fminf(rt[vA + u], o[u]);
            rt[(vA + u) ^ 31] = fminf(rt[(vA + u) ^ 31], o[u + 4]);
          }
        } else {
#pragma unroll
          for (int u = 0; u < 4; ++u) {
            rt[vA + u]        = fmaxf(rt[vA + u], o[u]);
            rt[(vA + u) ^ 31] = fmaxf(rt[(vA + u) ^ 31], o[u + 4]);
          }
        }
      }
    }
    // cross-lane xor passes: lane mask m = kb/2 .. 1, same v, keep min iff
    // (lane & m) == 0. Batches of 8 per array, one shared temp buffer.
    for (int m = kb >> 1; m >= 1; m >>= 1) {
      const bool lower = (lane & m) == 0;
#pragma unroll
      for (int c = 0; c < V; c += 8) {
        float o[8];
#pragma unroll
        for (int u = 0; u < 8; ++u) o[u] = __shfl_xor(rp[c + u], m, 64);
        if (lower) {
#pragma unroll
          for (int u = 0; u < 8; ++u) rp[c + u] = fminf(rp[c + u], o[u]);
        } else {
#pragma unroll
          for (int u = 0; u < 8; ++u) rp[c + u] = fmaxf(rp[c + u], o[u]);
        }
#pragma unroll
        for (int u = 0; u < 8; ++u) o[u] = __shfl_xor(rt[c + u], m, 64);
        if (lower) {
#pragma unroll
          for (int u = 0; u < 8; ++u) rt[c + u] = fminf(rt[c + u], o[u]);
        } else {
#pragma unroll
          for (int u = 0; u < 8; ++u) rt[c + u] = fmaxf(rt[c + u], o[u]);
        }
      }
    }
    // in-lane xor passes j = 16..1: static indices AND static direction
#pragma unroll
    for (int j = 16; j >= 1; j >>= 1) {
#pragma unroll
      for (int v = 0; v < V; ++v) {
        if ((v & j) == 0) {
          ce(rp[v], rp[v | j]);
          ce(rt[v], rt[v | j]);
        }
      }
    }
  }

  // ranks are matched at identical (lane, v) after both sorts
  float acc = 0.f;
#pragma unroll
  for (int v = 0; v < V; ++v) {
    const float d = rp[v] - rt[v];
    acc = fmaf(d, d, acc);
  }
#pragma unroll
  for (int off = 32; off > 0; off >>= 1) acc += __shfl_down(acc, off, 64);
  if (lane == 0) {
    unsafeAtomicAdd(out, acc * (1.0f / ((float)ROWS * (float)NCOL)));
  }
}

extern "C" void kernel_launch(void* const* d_in, const int* in_sizes, int n_in,
                              void* d_out, int out_size, void* d_ws, size_t ws_size,
                              hipStream_t stream) {
  const float* pred = (const float*)d_in[0];
  const float* targ = (const float*)d_in[1];
  float* out = (float*)d_out;

  hipMemsetAsync(out, 0, sizeof(float), stream);  // d_out is re-poisoned 0xAA
  sort_mse_kernel<<<ROWS / WPB, THREADS, 0, stream>>>(pred, targ, out);
}

// Round 5
// 246.255 us; speedup vs baseline: 2.1937x; 1.0938x over previous
//
#include <hip/hip_runtime.h>
#include <math.h>

#define ROWS 8192
#define NCOL 2048
#define V 32
#define WPB 4                 // waves (rows) per block
#define THREADS (WPB * 64)

// static compare-exchange: ascending, both indices compile-time
__device__ __forceinline__ void ce(float& a, float& b) {
  const float lo = fminf(a, b);
  const float hi = fmaxf(a, b);
  a = lo; b = hi;
}

// med3(a,b,-inf)=min(a,b); med3(a,b,+inf)=max(a,b). One VALU op per
// cross-lane compare-exchange, direction baked into per-pass constant.
__device__ __forceinline__ float ce_dir(float a, float b, float cdir) {
  return __builtin_amdgcn_fmed3f(a, b, cdir);
}

// One wave per row; lane holds elements e = lane*32 + v of both arrays in
// registers. Normalized bitonic sort (all compares ascending).
// Cross-lane passes: shuffle + single v_med3_f32 (direction constant per
// pass: -inf -> keep min, +inf -> keep max). In-lane passes: static min+max.
__global__ __launch_bounds__(THREADS, 4) void sort_mse_kernel(
    const float* __restrict__ pred, const float* __restrict__ targ,
    float* __restrict__ out) {
  const int lane = threadIdx.x & 63;
  const int wave = threadIdx.x >> 6;
  const int row = blockIdx.x * WPB + wave;
  const size_t base = (size_t)row * NCOL + (size_t)lane * V;

  float rp[V], rt[V];
  const float4* p4 = (const float4*)(pred + base);
  const float4* t4 = (const float4*)(targ + base);
#pragma unroll
  for (int q = 0; q < V / 4; ++q) {
    const float4 a = p4[q];
    rp[4 * q + 0] = a.x; rp[4 * q + 1] = a.y;
    rp[4 * q + 2] = a.z; rp[4 * q + 3] = a.w;
    const float4 b = t4[q];
    rt[4 * q + 0] = b.x; rt[4 * q + 1] = b.y;
    rt[4 * q + 2] = b.z; rt[4 * q + 3] = b.w;
  }

  // ---- Phase 1: stages k = 2..32, fully in-lane, fully static ----
#pragma unroll
  for (int k = 2; k <= V; k <<= 1) {
#pragma unroll
    for (int v = 0; v < V; ++v) {
      if ((v & (k >> 1)) == 0) {
        ce(rp[v], rp[v ^ (k - 1)]);
        ce(rt[v], rt[v ^ (k - 1)]);
      }
    }
#pragma unroll
    for (int j = k >> 2; j >= 1; j >>= 1) {
#pragma unroll
      for (int v = 0; v < V; ++v) {
        if ((v & j) == 0) {
          ce(rp[v], rp[v | j]);
          ce(rt[v], rt[v | j]);
        }
      }
    }
  }

  // ---- Phase 2: stages k = 64..2048 (kb = k/64 = 1..32) ----
  for (int kb = 1; kb <= 32; kb <<= 1) {
    // flip pass: partner lane = lane ^ (2kb-1), partner elem = v ^ 31,
    // keep min iff (lane & kb) == 0.
    {
      const int lm = 2 * kb - 1;
      const float cdir = (lane & kb) ? INFINITY : -INFINITY;
#pragma unroll
      for (int q = 0; q < 4; ++q) {
        const int vA = 4 * q;          // unit: vA..vA+3 and their ^31 partners
        float o[8];
#pragma unroll
        for (int u = 0; u < 4; ++u) {
          o[u]     = __shfl_xor(rp[(vA + u) ^ 31], lm, 64);
          o[u + 4] = __shfl_xor(rp[vA + u], lm, 64);
        }
#pragma unroll
        for (int u = 0; u < 4; ++u) {
          rp[vA + u]        = ce_dir(rp[vA + u],        o[u],     cdir);
          rp[(vA + u) ^ 31] = ce_dir(rp[(vA + u) ^ 31], o[u + 4], cdir);
        }
#pragma unroll
        for (int u = 0; u < 4; ++u) {
          o[u]     = __shfl_xor(rt[(vA + u) ^ 31], lm, 64);
          o[u + 4] = __shfl_xor(rt[vA + u], lm, 64);
        }
#pragma unroll
        for (int u = 0; u < 4; ++u) {
          rt[vA + u]        = ce_dir(rt[vA + u],        o[u],     cdir);
          rt[(vA + u) ^ 31] = ce_dir(rt[(vA + u) ^ 31], o[u + 4], cdir);
        }
      }
    }
    // cross-lane xor passes: lane mask m = kb/2 .. 1, same v,
    // keep min iff (lane & m) == 0. Lockstep same-v exchange: shuffles of a
    // batch all read old values before the med3 writes.
    for (int m = kb >> 1; m >= 1; m >>= 1) {
      const float cdir = (lane & m) ? INFINITY : -INFINITY;
#pragma unroll
      for (int c = 0; c < V; c += 8) {
        float o[8];
#pragma unroll
        for (int u = 0; u < 8; ++u) o[u] = __shfl_xor(rp[c + u], m, 64);
#pragma unroll
        for (int u = 0; u < 8; ++u) rp[c + u] = ce_dir(rp[c + u], o[u], cdir);
#pragma unroll
        for (int u = 0; u < 8; ++u) o[u] = __shfl_xor(rt[c + u], m, 64);
#pragma unroll
        for (int u = 0; u < 8; ++u) rt[c + u] = ce_dir(rt[c + u], o[u], cdir);
      }
    }
    // in-lane xor passes j = 16..1: static indices AND static direction
#pragma unroll
    for (int j = 16; j >= 1; j >>= 1) {
#pragma unroll
      for (int v = 0; v < V; ++v) {
        if ((v & j) == 0) {
          ce(rp[v], rp[v | j]);
          ce(rt[v], rt[v | j]);
        }
      }
    }
  }

  // ranks are matched at identical (lane, v) after both sorts
  float acc = 0.f;
#pragma unroll
  for (int v = 0; v < V; ++v) {
    const float d = rp[v] - rt[v];
    acc = fmaf(d, d, acc);
  }
#pragma unroll
  for (int off = 32; off > 0; off >>= 1) acc += __shfl_down(acc, off, 64);
  if (lane == 0) {
    unsafeAtomicAdd(out, acc * (1.0f / ((float)ROWS * (float)NCOL)));
  }
}

extern "C" void kernel_launch(void* const* d_in, const int* in_sizes, int n_in,
                              void* d_out, int out_size, void* d_ws, size_t ws_size,
                              hipStream_t stream) {
  const float* pred = (const float*)d_in[0];
  const float* targ = (const float*)d_in[1];
  float* out = (float*)d_out;

  hipMemsetAsync(out, 0, sizeof(float), stream);  // d_out is re-poisoned 0xAA
  sort_mse_kernel<<<ROWS / WPB, THREADS, 0, stream>>>(pred, targ, out);
}